// Round 7
// baseline (634.060 us; speedup 1.0000x reference)
//
#include <hip/hip_runtime.h>
#include <math.h>

#define ROWS 65536
#define DIM  256
#define KC   1024
#define NQ   (ROWS * DIM)

// ---- ws layout (bytes) ----
// [0]      double lossacc
// [16]     int    counts[1024]          (ends 4112)
// [4224]   float  B32[1024]             (ends 8320)
// [8320]   float  Arr[65536]            (ends 270464)
// [270464] u64    packed[65536]         (ends 794752)   (distbits<<32)|idx

// ---------------------------------------------------------------------------
// Wave-cooperative numpy pairwise sum-of-squares: 16 lanes per row (verified
// bit-exact R4/R6). Lane (h,l) owns numpy accumulator r_l of half h; combine
// via shfl_xor in numpy's tree order (fp32 add commutative).
// ---------------------------------------------------------------------------
__global__ __launch_bounds__(256) void k_prep16(const float* __restrict__ src,
                                                float* __restrict__ dst,
                                                int nrows) {
    int lane = threadIdx.x & 63;
    int wv   = threadIdx.x >> 6;
    int rg   = lane >> 4;
    int sub  = lane & 15;
    int h    = sub >> 3;
    int l    = sub & 7;
    int row  = blockIdx.x * 16 + wv * 4 + rg;
    if (row >= nrows) return;
    const float* a = src + (size_t)row * DIM + h * 128 + l;
    float x = a[0];
    float r = __fmul_rn(x, x);
#pragma unroll
    for (int k = 1; k < 16; ++k) {
        float y = a[8 * k];
        r = __fadd_rn(r, __fmul_rn(y, y));
    }
    float t;
    t = __shfl_xor(r, 1, 64);  r = __fadd_rn(r, t);
    t = __shfl_xor(r, 2, 64);  r = __fadd_rn(r, t);
    t = __shfl_xor(r, 4, 64);  r = __fadd_rn(r, t);
    t = __shfl_xor(r, 8, 64);  r = __fadd_rn(r, t);
    if (sub == 0) dst[row] = r;
}

// ---------------- K1: fp32 dist + first-index argmin -----------------------
// R2's proven shape (256 thr, 8x8 acc, 84 VGPR measured) + two fixes:
//  (a) split-K=2: blockIdx.y selects cols [y*512, y*512+512) -> 1024 blocks
//      = 4/CU (R2 was grid-starved at 2/CU); merge via packed-u64 atomicMin.
//  (b) col-ownership swizzle: thread tx owns cols tx+16j -> Es fragment
//      reads are 8 conflict-free ds_read_b32 (16 consecutive banks, 4-way
//      broadcast free) instead of R2's 4-way-conflicted tx*8 b128 reads
//      (5.97e7 conflicts = ~20% tax).
// Transposed LDS [d][r], LSTR=132. Each acc[i][j] is ONE ascending-d fmaf
// chain from 0 over d=0..255 -> bit-identical to OpenBLAS sgemm. Fold uses
// fl(fl(A+B) - fl(2*dot)); strict < keeps lowest c (c ascends in j and cb).
// NO launch_bounds min clause (R3: (256,4) clamped to 64 VGPR -> 1.1 GB spill).
#define TM 128
#define TN 128
#define TD 32
#define LSTR 132

__global__ __launch_bounds__(256) void k_pass1(
    const float* __restrict__ X, const float* __restrict__ E,
    const float* __restrict__ B32, const float* __restrict__ Arr,
    unsigned long long* __restrict__ packed)
{
    __shared__ float sm[2 * TD * LSTR];   // 33792 B -> 4 blocks/CU
    float* Xs = sm;                 // [TD][LSTR]  (d-major, row minor)
    float* Es = sm + TD * LSTR;     // [TD][LSTR]  (d-major, col minor)

    const int tid = threadIdx.x;
    const int tx = tid & 15;        // owns cols tx + 16j, j<8
    const int ty = tid >> 4;        // owns rows ty*8 .. ty*8+7
    const int rowbase = blockIdx.x * TM;
    const int colbase = blockIdx.y * 512;

    float a8[8];
#pragma unroll
    for (int i = 0; i < 8; ++i) a8[i] = Arr[rowbase + ty * 8 + i];

    float v1[8]; int i1[8];
#pragma unroll
    for (int i = 0; i < 8; ++i) { v1[i] = 3.0e38f; i1[i] = 0; }

    for (int cb = 0; cb < 512; cb += TN) {
        float acc[8][8];
#pragma unroll
        for (int i = 0; i < 8; ++i)
#pragma unroll
            for (int j = 0; j < 8; ++j) acc[i][j] = 0.0f;

        for (int dc = 0; dc < DIM; dc += TD) {
            __syncthreads();
            // stage 128x32 of X and E, transposed into LDS
#pragma unroll
            for (int k = 0; k < 4; ++k) {
                int fi  = tid + k * 256;          // 0..1023
                int r   = fi >> 3;                // 0..127
                int dd4 = (fi & 7) * 4;           // 0,4,...,28
                float4 xv = *(const float4*)(X + (size_t)(rowbase + r) * DIM + dc + dd4);
                Xs[(dd4 + 0) * LSTR + r] = xv.x;
                Xs[(dd4 + 1) * LSTR + r] = xv.y;
                Xs[(dd4 + 2) * LSTR + r] = xv.z;
                Xs[(dd4 + 3) * LSTR + r] = xv.w;
                float4 ev = *(const float4*)(E + (size_t)(colbase + cb + r) * DIM + dc + dd4);
                Es[(dd4 + 0) * LSTR + r] = ev.x;
                Es[(dd4 + 1) * LSTR + r] = ev.y;
                Es[(dd4 + 2) * LSTR + r] = ev.z;
                Es[(dd4 + 3) * LSTR + r] = ev.w;
            }
            __syncthreads();

#pragma unroll 4
            for (int dd = 0; dd < TD; ++dd) {
                float xr[8], er[8];
                float4 t0 = *(float4*)&Xs[dd * LSTR + ty * 8];
                float4 t1 = *(float4*)&Xs[dd * LSTR + ty * 8 + 4];
                xr[0]=t0.x; xr[1]=t0.y; xr[2]=t0.z; xr[3]=t0.w;
                xr[4]=t1.x; xr[5]=t1.y; xr[6]=t1.z; xr[7]=t1.w;
#pragma unroll
                for (int j = 0; j < 8; ++j)
                    er[j] = Es[dd * LSTR + tx + 16 * j];   // conflict-free b32
#pragma unroll
                for (int i = 0; i < 8; ++i)
#pragma unroll
                    for (int j = 0; j < 8; ++j)
                        acc[i][j] = fmaf(xr[i], er[j], acc[i][j]);
            }
        }

        // fold: dist = fl(fl(A + B) - fl(2*dot)); strict < keeps lowest c
#pragma unroll
        for (int j = 0; j < 8; ++j) {
            int c = colbase + cb + tx + 16 * j;
            float b = B32[c];
#pragma unroll
            for (int i = 0; i < 8; ++i) {
                float Cv  = __fmul_rn(2.0f, acc[i][j]);
                float t1v = __fadd_rn(a8[i], b);
                float dv  = __fsub_rn(t1v, Cv);
                if (dv < v1[i]) { v1[i] = dv; i1[i] = c; }
            }
        }
    }

    // merge (val, idx) across the 16 col-threads per row via LDS
    __syncthreads();
    float* Mv = sm;                        // [128][16] floats, bytes 0..8192
    int*   Mi = (int*)(sm + 2048);         // [128][16] ints, bytes 8192..16384
#pragma unroll
    for (int i = 0; i < 8; ++i) {
        int r = ty * 8 + i;
        Mv[r * 16 + tx] = v1[i];
        Mi[r * 16 + tx] = i1[i];
    }
    __syncthreads();
    if (tid < TM) {
        int r = tid;
        float bv = Mv[r * 16];
        int   bi = Mi[r * 16];
        for (int t = 1; t < 16; ++t) {
            float av = Mv[r * 16 + t];
            int   ai = Mi[r * 16 + t];
            if (av < bv || (av == bv && ai < bi)) { bv = av; bi = ai; }
        }
        // dist > 0 always (A ~ 256 dominates) -> IEEE bits order-preserving;
        // ties resolve to lower idx -> global first-index semantics.
        unsigned long long pk =
            ((unsigned long long)__float_as_uint(bv) << 32) |
            (unsigned long long)(unsigned)bi;
        atomicMin(&packed[rowbase + r], pk);
    }
}

// ---------------- K3: gather quantized + fp64 loss accumulation ------------
__global__ __launch_bounds__(256) void k_out(
    const float* __restrict__ X, const float* __restrict__ E,
    const unsigned long long* __restrict__ packed, float* __restrict__ out0,
    double* __restrict__ lossacc)
{
    const int NF4 = NQ / 4;
    double s = 0.0;
    for (int g = blockIdx.x * blockDim.x + threadIdx.x; g < NF4;
         g += gridDim.x * blockDim.x) {
        int row = g >> 6;
        int d4  = g & 63;
        int j = (int)(packed[row] & 0xffffffffULL);
        float4 q = *(const float4*)(E + (size_t)j * DIM + d4 * 4);
        float4 x = *(const float4*)(X + (size_t)g * 4);
        *(float4*)(out0 + (size_t)g * 4) = q;
        double dx;
        dx = (double)q.x - (double)x.x; s = fma(dx, dx, s);
        dx = (double)q.y - (double)x.y; s = fma(dx, dx, s);
        dx = (double)q.z - (double)x.z; s = fma(dx, dx, s);
        dx = (double)q.w - (double)x.w; s = fma(dx, dx, s);
    }
#pragma unroll
    for (int off = 32; off > 0; off >>= 1) s += __shfl_down(s, off, 64);
    __shared__ double wsum[4];
    int lane = threadIdx.x & 63, wv = threadIdx.x >> 6;
    if (lane == 0) wsum[wv] = s;
    __syncthreads();
    if (threadIdx.x == 0) {
        double t = wsum[0] + wsum[1] + wsum[2] + wsum[3];
        atomicAdd(lossacc, t);
    }
}

// ---------------- K3b: index output + histogram ----------------------------
__global__ __launch_bounds__(256) void k_idxout(
    const unsigned long long* __restrict__ packed, float* __restrict__ out1,
    int* __restrict__ counts)
{
    __shared__ int h[KC];
    for (int i = threadIdx.x; i < KC; i += 256) h[i] = 0;
    __syncthreads();
    int r = blockIdx.x * 256 + threadIdx.x;   // grid 256*256 = 65536 exact
    int j = (int)(packed[r] & 0xffffffffULL);
    out1[r] = (float)j;
    atomicAdd(&h[j], 1);
    __syncthreads();
    for (int i = threadIdx.x; i < KC; i += 256)
        if (h[i]) atomicAdd(&counts[i], h[i]);
}

// ---------------- K4: perplexity + loss finalize ---------------------------
__global__ void k_fin(const int* __restrict__ counts,
                      const double* __restrict__ lossacc,
                      float* __restrict__ out_pl)
{
    __shared__ double sh[256];
    double s = 0.0;
    for (int i = threadIdx.x; i < KC; i += 256) {
        double p = (double)counts[i] / 65536.0;
        s += p * log(p + 1.1920928955078125e-07);   // EPS = fp32 eps exactly
    }
    sh[threadIdx.x] = s;
    __syncthreads();
    for (int off = 128; off > 0; off >>= 1) {
        if (threadIdx.x < off) sh[threadIdx.x] += sh[threadIdx.x + off];
        __syncthreads();
    }
    if (threadIdx.x == 0) {
        out_pl[0] = (float)exp(-sh[0]);
        out_pl[1] = (float)((*lossacc / (double)NQ) * 1.1);  // q + 0.1*e
    }
}

extern "C" void kernel_launch(void* const* d_in, const int* in_sizes, int n_in,
                              void* d_out, int out_size, void* d_ws, size_t ws_size,
                              hipStream_t stream) {
    const float* X = (const float*)d_in[0];
    const float* E = (const float*)d_in[1];
    float* out = (float*)d_out;
    char* ws = (char*)d_ws;

    double* lossacc = (double*)(ws + 0);
    int*    counts  = (int*)(ws + 16);
    float*  B32     = (float*)(ws + 4224);
    float*  Arr     = (float*)(ws + 8320);
    unsigned long long* packed = (unsigned long long*)(ws + 270464);

    hipMemsetAsync(ws, 0, 4224, stream);               // lossacc + counts
    hipMemsetAsync(ws + 270464, 0xFF, 524288, stream); // packed = u64 max

    hipLaunchKernelGGL(k_prep16, dim3(KC / 16),   dim3(256), 0, stream,
                       E, B32, KC);
    hipLaunchKernelGGL(k_prep16, dim3(ROWS / 16), dim3(256), 0, stream,
                       X, Arr, ROWS);
    hipLaunchKernelGGL(k_pass1, dim3(ROWS / TM, 2), dim3(256), 0, stream,
                       X, E, B32, Arr, packed);
    hipLaunchKernelGGL(k_out,   dim3(2048), dim3(256), 0, stream,
                       X, E, packed, out, lossacc);
    hipLaunchKernelGGL(k_idxout, dim3(256), dim3(256), 0, stream,
                       packed, out + NQ, counts);
    hipLaunchKernelGGL(k_fin,   dim3(1),   dim3(256), 0, stream,
                       counts, lossacc, out + NQ + 65536);
}